// Round 11
// baseline (307.302 us; speedup 1.0000x reference)
//
#include <hip/hip_runtime.h>
#include <hip/hip_cooperative_groups.h>
#include <math.h>

namespace cg = cooperative_groups;

// Problem constants
#define NB   256
#define TT   36
#define FF   50
#define PP   80
#define KK   161
#define NITER 100
#define LAMB 0.1f

#define CODE_SZ (NB*KK*FF)          // 2,060,800
#define D_OFF   CODE_SZ
#define R_OFF   (CODE_SZ + TT*KK)

// ws float layout:
// [1] = wn^2 accumulator; [16..79] = ssq partials (64 k_build blocks)
// [80..179] = beta momentum table (betas[it], it=1..99)
// [WSA1..] A1 image (D):   [Mt1:3][kt:6][h:2][512] f16 = 9216 floats
// [WSA2..] A2 image (D^T): [Mt2:6][kt:3][h:2][512] f16 = 9216 floats
#define WSA1 256
#define WSA2 (256 + 9216)

typedef _Float16 half8 __attribute__((ext_vector_type(8)));
typedef __fp16 fp16x2 __attribute__((ext_vector_type(2)));   // cvt_pkrtz result type
typedef float f32x4  __attribute__((ext_vector_type(4)));
typedef float f32x16 __attribute__((ext_vector_type(16)));
#define MFMA_16(A,B,C) __builtin_amdgcn_mfma_f32_16x16x32_f16(A,B,C,0,0,0)
#define MFMA_32(A,B,C) __builtin_amdgcn_mfma_f32_32x32x16_f16(A,B,C,0,0,0)

// packed f32->f16 (RTZ) x4 into one u64 (2x v_cvt_pkrtz_f16_f32)
static __device__ __forceinline__ unsigned long long pack4(float a, float b,
                                                           float c, float d) {
    union { unsigned long long u; fp16x2 h[2]; } r;
    r.h[0] = __builtin_amdgcn_cvt_pkrtz(a, b);
    r.h[1] = __builtin_amdgcn_cvt_pkrtz(c, d);
    return r.u;
}

// ---------------------------------------------------------------------------
// K1 (grid 64): build D (blk0 -> d_out), ssq partials -> ws[16+b], beta table
// (blk0 lane0 -> ws[80..179]), pack f16 hi/lo MFMA A-operand images for D
// (GEMM1 16x16x32) and D^T (GEMM2 32x32x16).
__global__ __launch_bounds__(256) void k_build(const float* __restrict__ rr,
                                               const float* __restrict__ th,
                                               float* __restrict__ out,
                                               float* __restrict__ ws) {
    __shared__ float Dl[TT*KK];
    __shared__ float red[256];
    int tid = threadIdx.x, b = blockIdx.x;
    for (int e = tid; e < TT*KK; e += 256) {
        int t = e / KK, k = e % KK;
        float v;
        if (k == 0) v = 1.f;
        else if (k <= PP) { int p = k - 1;     v = powf(rr[p], (float)t) * cosf((float)t * th[p]); }
        else              { int p = k - 1 - PP; v = powf(rr[p], (float)t) * sinf((float)t * th[p]); }
        Dl[e] = v;
        if (b == 0) out[D_OFF + e] = v;
    }
    // beta momentum table: identical float ops to the original in-loop chain
    if (b == 0 && tid == 0) {
        float t = 0.5f * (1.f + sqrtf(5.f));   // t_1 (after peeled iter 0)
        ws[80] = 0.f;
        for (int it = 1; it < NITER; ++it) {
            float tn = 0.5f * (1.f + sqrtf(1.f + 4.f*t*t));
            ws[80 + it] = (t - 1.f) / tn;
            t = tn;
        }
    }
    __syncthreads();
    float ssq = 0.f;
    for (int p = b*256 + tid; p < KK*KK; p += 64*256) {
        int k1 = p / KK, k2 = p % KK;
        float s = 0.f;
        for (int t = 0; t < TT; ++t) s += Dl[t*KK + k1] * Dl[t*KK + k2];
        ssq += s * s;
    }
    red[tid] = ssq;
    __syncthreads();
    for (int off = 128; off > 0; off >>= 1) {
        if (tid < off) red[tid] += red[tid + off];
        __syncthreads();
    }
    if (tid == 0) { ws[16 + b] = red[0]; if (b == 0) ws[1] = 0.f; }

    // A1: lane l holds A[m=l&15][k=8*(l>>4)+i] per 16x16x32 tile
    _Float16* a1 = (_Float16*)(ws + WSA1);
    for (int e = b*256 + tid; e < 3*6*2*512; e += 64*256) {
        int fp = e & 511, r = e >> 9;       // r = (Mt1*6+kt)*2 + h
        int h = r & 1, mk = r >> 1;
        int l = fp >> 3, i = fp & 7;
        int t = (mk / 6) * 16 + (l & 15);
        int j = (mk % 6) * 32 + ((l >> 4) << 3) + i;
        float v = (t < TT && j < KK) ? Dl[t*KK + j] : 0.f;
        _Float16 hi = (_Float16)v;
        a1[e] = h ? (_Float16)(v - (float)hi) : hi;
    }
    // A2 (D^T): lane l holds A[m=l&31][k=8*(l>>5)+i] per 32x32x16 tile
    _Float16* a2 = (_Float16*)(ws + WSA2);
    for (int e = b*256 + tid; e < 6*3*2*512; e += 64*256) {
        int fp = e & 511, r = e >> 9;       // r = (Mt2*3+kt)*2 + h
        int h = r & 1, mk = r >> 1;
        int l = fp >> 3, i = fp & 7;
        int m = (mk / 3) * 32 + (l & 31);
        int t = (mk % 3) * 16 + ((l >> 5) << 3) + i;
        float v = (m < KK && t < TT) ? Dl[t*KK + m] : 0.f;
        _Float16 hi = (_Float16)v;
        a2[e] = h ? (_Float16)(v - (float)hi) : hi;
    }
}

// ---------------------------------------------------------------------------
// K2: fused FISTA, BOTH reweighting phases in one cooperative kernel.
// R10 lesson: f16 state breaks numerics (momentum amplifies quantization,
// absmax 0.60) -> f32 state (R9 math, bitwise identical here). R9 budget:
// 113.2us x2 dispatches + ~54us of k_build + 3x launch overhead. This round
// removes one launch + phase1's head GEMM / x re-stage / prev global reads
// (c-vector kept in cvf[16] registers; prev = phase0's xo registers) +
// phase0's dead code store. grid 256 = 1 block/CU, co-residency guaranteed;
// ws[1] read post-grid.sync via device-scope atomic load (XCD L2 safety).
// GEMM1 (z = D y): 16x16x32, wave = (Mt1 = w>>2, nt1 = w&3).
// GEMM2 (w = D^T z): 32x32x16, wave = (Mt2 = w>>1, nh = w&1).
__global__ __launch_bounds__(768, 3) void k_fista_fused(float* __restrict__ ws,
                                                        const float* __restrict__ x,
                                                        float* __restrict__ out) {
    __shared__ _Float16 Ys[4*6*512];   // 24,576 B: [nt16:4][kt32:6][512]
    __shared__ _Float16 Zs[2*3*512];   //  6,144 B: [nh:2][kt16:3][512]
    __shared__ float bts[NITER];       //    400 B: beta momentum table
    __shared__ float ws1_s;            // wnorm broadcast after grid sync
    int tid = threadIdx.x;
    int w = tid >> 6, l = tid & 63;
    int n = blockIdx.x;

    // ---- stage x -> Zs (f16 hi, GEMM2 B-frag image, k-dim = t)
    const float* xb = x + n*TT*FF;
    for (int e = tid; e < 3072; e += 768) {
        int t = e >> 6, c64 = e & 63;
        float v = (t < TT && c64 < FF) ? xb[t*FF + c64] : 0.f;
        int nh = c64 >> 5, c = c64 & 31;
        int kt = t >> 4, kk = t & 15;
        int ofs = ((((kk >> 3) << 5) + c) << 3) + (kk & 7);
        Zs[((nh*3 + kt) << 9) + ofs] = (_Float16)v;
    }
    if (tid < NITER) bts[tid] = ws[80 + tid];

    // ---- L-norm: wave butterfly over the 64 k_build partials
    float pv = ws[16 + l];
    #pragma unroll
    for (int off = 32; off > 0; off >>= 1) pv += __shfl_xor(pv, off);
    float linv = rsqrtf(pv);

    int Mt1 = w >> 2, nt1 = w & 3;     // GEMM1 role
    int Mt2 = w >> 1, nh  = w & 1;     // GEMM2 role
    const _Float16* a1g = (const _Float16*)(ws + WSA1);
    const _Float16* a2g = (const _Float16*)(ws + WSA2);
    half8 a1[6][2], a2[3][2];
    #pragma unroll
    for (int kt = 0; kt < 6; ++kt)
        #pragma unroll
        for (int h = 0; h < 2; ++h)
            a1[kt][h] = *(const half8*)(a1g + ((((Mt1*6 + kt)*2 + h) << 9) + (l << 3)));
    #pragma unroll
    for (int kt = 0; kt < 3; ++kt)
        #pragma unroll
        for (int h = 0; h < 2; ++h)
            a2[kt][h] = *(const half8*)(a2g + ((((Mt2*3 + kt)*2 + h) << 9) + (l << 3)));

    // held zero accumulators (loop-invariant C operands for first MFMA)
    f32x16 z16;
    #pragma unroll
    for (int r = 0; r < 16; ++r) z16[r] = 0.f;
    f32x4 z4 = {0.f, 0.f, 0.f, 0.f};
    __syncthreads();

    // ---- head GEMM2: acc = D^T @ f16(x)  (hi+lo, full precision for c)
    f32x16 acc;
    {
        half8 bh = *(const half8*)&Zs[((nh*3 + 0) << 9) + (l << 3)];
        acc = MFMA_32(a2[0][0], bh, z16);
        acc = MFMA_32(a2[0][1], bh, acc);
    }
    #pragma unroll
    for (int kt = 1; kt < 3; ++kt) {
        half8 bh = *(const half8*)&Zs[((nh*3 + kt) << 9) + (l << 3)];
        acc = MFMA_32(a2[kt][0], bh, acc);
        acc = MFMA_32(a2[kt][1], bh, acc);
    }

    int cl = l & 15, q = l >> 4;       // GEMM1 C addressing
    int nloc = l & 31, s5 = l >> 5;    // GEMM2 C addressing
    int nt16 = nh*2 + (nloc >> 4);
    int fcol = nh*32 + nloc;           // global f of owned columns
    int zofs = ((((q >> 1) << 5) + (nt1 & 1)*16 + cl) << 3) + ((q & 1) << 2);
    int znh = nt1 >> 1;

    // c-vector retained in registers for BOTH phases (guarded, f32)
    float cvf[16];
    #pragma unroll
    for (int gq = 0; gq < 4; ++gq) {
        int k0 = Mt2*32 + 8*gq + 4*s5;
        #pragma unroll
        for (int j = 0; j < 4; ++j)
            cvf[gq*4 + j] = (k0 + j < KK && fcol < FF) ? linv * acc[gq*4 + j] : 0.f;
    }

    float blo[4][4], bhi[4][4], xo[4][4], yo[4][4];
    float wlv = LAMB * linv;           // uniform shrink width (phase 0)

    // ================= PHASE 0 =================
    // peeled iteration 0: x1 = shrink(c), y1 = x1
    #pragma unroll
    for (int gq = 0; gq < 4; ++gq) {
        float yn4[4];
        #pragma unroll
        for (int j = 0; j < 4; ++j) {
            float cvv = cvf[gq*4 + j];
            blo[gq][j] = -cvv - wlv;
            bhi[gq][j] = wlv - cvv;
            float xn = cvv - __builtin_amdgcn_fmed3f(cvv, -wlv, wlv);
            xo[gq][j] = xn; yo[gq][j] = xn;
            yn4[j] = xn;
        }
        int yofs = ((gq*16 + cl) << 3) + (s5 << 2);
        *(unsigned long long*)&Ys[((nt16*6 + Mt2) << 9) + yofs] =
            pack4(yn4[0], yn4[1], yn4[2], yn4[3]);
    }
    __syncthreads();

    for (int it = 1; it < NITER; ++it) {
        float beta = bts[it];
        f32x4 zz;
        {
            half8 bh = *(const half8*)&Ys[((nt1*6 + 0) << 9) + (l << 3)];
            zz = MFMA_16(a1[0][0], bh, z4);
        }
        #pragma unroll
        for (int kt = 1; kt < 6; ++kt) {
            half8 bh = *(const half8*)&Ys[((nt1*6 + kt) << 9) + (l << 3)];
            zz = MFMA_16(a1[kt][0], bh, zz);
        }
        *(unsigned long long*)&Zs[((znh*3 + Mt1) << 9) + zofs] =
            pack4(zz[0], zz[1], zz[2], zz[3]);
        __syncthreads();

        {
            half8 bh = *(const half8*)&Zs[((nh*3 + 0) << 9) + (l << 3)];
            acc = MFMA_32(a2[0][0], bh, z16);
        }
        #pragma unroll
        for (int kt = 1; kt < 3; ++kt) {
            half8 bh = *(const half8*)&Zs[((nh*3 + kt) << 9) + (l << 3)];
            acc = MFMA_32(a2[kt][0], bh, acc);
        }
        #pragma unroll
        for (int gq = 0; gq < 4; ++gq) {
            float yn4[4];
            #pragma unroll
            for (int j = 0; j < 4; ++j) {
                float ay = fmaf(-linv, acc[gq*4 + j], yo[gq][j]);
                float xn = ay - __builtin_amdgcn_fmed3f(ay, blo[gq][j], bhi[gq][j]);
                float yn = fmaf(beta, xn - xo[gq][j], xn);
                xo[gq][j] = xn; yo[gq][j] = yn;
                yn4[j] = yn;
            }
            int yofs = ((gq*16 + cl) << 3) + (s5 << 2);
            *(unsigned long long*)&Ys[((nt16*6 + Mt2) << 9) + yofs] =
                pack4(yn4[0], yn4[1], yn4[2], yn4[3]);
        }
        __syncthreads();
    }

    // ---- wnorm from registers (phase0 code never touches global)
    {
        float s = 0.f;
        #pragma unroll
        for (int gq = 0; gq < 4; ++gq) {
            int k0 = Mt2*32 + 8*gq + 4*s5;
            #pragma unroll
            for (int j = 0; j < 4; ++j) {
                if (k0 + j < KK && fcol < FF) {
                    float wn = 1.f / (fabsf(xo[gq][j]) + 0.01f);
                    s += wn * wn;
                }
            }
        }
        #pragma unroll
        for (int off = 32; off > 0; off >>= 1) s += __shfl_down(s, off);
        float* red = (float*)Zs;
        if (l == 0) red[w] = s;
        __syncthreads();
        if (tid == 0) {
            float t = 0.f;
            #pragma unroll
            for (int i = 0; i < 12; ++i) t += red[i];
            atomicAdd(&ws[1], t);
        }
    }

    cg::this_grid().sync();

    if (tid == 0)
        ws1_s = __hip_atomic_load(&ws[1], __ATOMIC_RELAXED, __HIP_MEMORY_SCOPE_AGENT);
    __syncthreads();
    float fac = (float)KK * LAMB * linv * rsqrtf(ws1_s);

    // ================= PHASE 1 =================
    // peeled iteration 0: wl from phase0's xo registers (== stored code)
    #pragma unroll
    for (int gq = 0; gq < 4; ++gq) {
        int k0 = Mt2*32 + 8*gq + 4*s5;
        float yn4[4];
        #pragma unroll
        for (int j = 0; j < 4; ++j) {
            float cvv = cvf[gq*4 + j];
            float wle = (k0 + j < KK && fcol < FF)
                        ? fac / (fabsf(xo[gq][j]) + 0.01f) : 0.f;
            blo[gq][j] = -cvv - wle;
            bhi[gq][j] = wle - cvv;
            float xn = cvv - __builtin_amdgcn_fmed3f(cvv, -wle, wle);
            xo[gq][j] = xn; yo[gq][j] = xn;
            yn4[j] = xn;
        }
        int yofs = ((gq*16 + cl) << 3) + (s5 << 2);
        *(unsigned long long*)&Ys[((nt16*6 + Mt2) << 9) + yofs] =
            pack4(yn4[0], yn4[1], yn4[2], yn4[3]);
    }
    __syncthreads();

    for (int it = 1; it < NITER; ++it) {
        float beta = bts[it];
        f32x4 zz;
        {
            half8 bh = *(const half8*)&Ys[((nt1*6 + 0) << 9) + (l << 3)];
            zz = MFMA_16(a1[0][0], bh, z4);
        }
        #pragma unroll
        for (int kt = 1; kt < 6; ++kt) {
            half8 bh = *(const half8*)&Ys[((nt1*6 + kt) << 9) + (l << 3)];
            zz = MFMA_16(a1[kt][0], bh, zz);
        }
        *(unsigned long long*)&Zs[((znh*3 + Mt1) << 9) + zofs] =
            pack4(zz[0], zz[1], zz[2], zz[3]);
        __syncthreads();

        {
            half8 bh = *(const half8*)&Zs[((nh*3 + 0) << 9) + (l << 3)];
            acc = MFMA_32(a2[0][0], bh, z16);
        }
        #pragma unroll
        for (int kt = 1; kt < 3; ++kt) {
            half8 bh = *(const half8*)&Zs[((nh*3 + kt) << 9) + (l << 3)];
            acc = MFMA_32(a2[kt][0], bh, acc);
        }
        #pragma unroll
        for (int gq = 0; gq < 4; ++gq) {
            float yn4[4];
            #pragma unroll
            for (int j = 0; j < 4; ++j) {
                float ay = fmaf(-linv, acc[gq*4 + j], yo[gq][j]);
                float xn = ay - __builtin_amdgcn_fmed3f(ay, blo[gq][j], bhi[gq][j]);
                float yn = fmaf(beta, xn - xo[gq][j], xn);
                xo[gq][j] = xn; yo[gq][j] = yn;
                yn4[j] = yn;
            }
            int yofs = ((gq*16 + cl) << 3) + (s5 << 2);
            *(unsigned long long*)&Ys[((nt16*6 + Mt2) << 9) + yofs] =
                pack4(yn4[0], yn4[1], yn4[2], yn4[3]);
        }
        __syncthreads();
    }

    // ---- store final code (phase 1 only)
    #pragma unroll
    for (int gq = 0; gq < 4; ++gq) {
        int k0 = Mt2*32 + 8*gq + 4*s5;
        #pragma unroll
        for (int j = 0; j < 4; ++j) {
            int k = k0 + j;
            if (k < KK && fcol < FF)
                out[(size_t)n*KK*FF + k*FF + fcol] = xo[gq][j];
        }
    }

    // ---- fused reconst: f16(code) into Ys, GEMM1 pass (hi+lo), store
    #pragma unroll
    for (int gq = 0; gq < 4; ++gq) {
        int yofs = ((gq*16 + cl) << 3) + (s5 << 2);
        *(unsigned long long*)&Ys[((nt16*6 + Mt2) << 9) + yofs] =
            pack4(xo[gq][0], xo[gq][1], xo[gq][2], xo[gq][3]);
    }
    __syncthreads();
    {
        f32x4 za, zb;
        {
            half8 bh = *(const half8*)&Ys[((nt1*6 + 0) << 9) + (l << 3)];
            za = MFMA_16(a1[0][0], bh, z4);
            zb = MFMA_16(a1[0][1], bh, z4);
        }
        #pragma unroll
        for (int kt = 1; kt < 6; ++kt) {
            half8 bh = *(const half8*)&Ys[((nt1*6 + kt) << 9) + (l << 3)];
            za = MFMA_16(a1[kt][0], bh, za);
            zb = MFMA_16(a1[kt][1], bh, zb);
        }
        f32x4 zz = za + zb;
        int fcol2 = nt1*16 + cl;
        #pragma unroll
        for (int r = 0; r < 4; ++r) {
            int t = Mt1*16 + q*4 + r;
            if (t < TT && fcol2 < FF)
                out[R_OFF + (size_t)n*TT*FF + t*FF + fcol2] = zz[r];
        }
    }
}

// ---------------------------------------------------------------------------
extern "C" void kernel_launch(void* const* d_in, const int* in_sizes, int n_in,
                              void* d_out, int out_size, void* d_ws, size_t ws_size,
                              hipStream_t stream) {
    const float* x  = (const float*)d_in[0];
    const float* rr = (const float*)d_in[1];
    const float* th = (const float*)d_in[2];
    float* out = (float*)d_out;
    float* ws  = (float*)d_ws;

    hipLaunchKernelGGL(k_build, dim3(64), dim3(256), 0, stream, rr, th, out, ws);
    void* args[] = { (void*)&ws, (void*)&x, (void*)&out };
    hipLaunchCooperativeKernel((const void*)k_fista_fused, dim3(NB), dim3(768),
                               args, 0, stream);
}

// Round 12
// 279.705 us; speedup vs baseline: 1.0987x; 1.0987x over previous
//
#include <hip/hip_runtime.h>
#include <math.h>

// Problem constants
#define NB   256
#define TT   36
#define FF   50
#define PP   80
#define KK   161
#define NITER 100
#define LAMB 0.1f

#define CODE_SZ (NB*KK*FF)          // 2,060,800
#define D_OFF   CODE_SZ
#define R_OFF   (CODE_SZ + TT*KK)

// ws float layout:
// [1] = wn^2 accumulator; [16..79] = ssq partials (64 k_build blocks)
// [80..179] = beta momentum table (betas[it], it=1..99)
// [WSA1..] A1 image (D):   [Mt1:3][kt:6][h:2][512] f16 = 9216 floats
// [WSA2..] A2 image (D^T): [Mt2:6][kt:3][h:2][512] f16 = 9216 floats
#define WSA1 256
#define WSA2 (256 + 9216)

typedef _Float16 half8 __attribute__((ext_vector_type(8)));
typedef __fp16 fp16x2 __attribute__((ext_vector_type(2)));   // cvt_pkrtz result type
typedef float f32x4  __attribute__((ext_vector_type(4)));
typedef float f32x16 __attribute__((ext_vector_type(16)));
#define MFMA_16(A,B,C) __builtin_amdgcn_mfma_f32_16x16x32_f16(A,B,C,0,0,0)
#define MFMA_32(A,B,C) __builtin_amdgcn_mfma_f32_32x32x16_f16(A,B,C,0,0,0)

// packed f32->f16 (RTZ) x4 into one u64 (2x v_cvt_pkrtz_f16_f32)
static __device__ __forceinline__ unsigned long long pack4(float a, float b,
                                                           float c, float d) {
    union { unsigned long long u; fp16x2 h[2]; } r;
    r.h[0] = __builtin_amdgcn_cvt_pkrtz(a, b);
    r.h[1] = __builtin_amdgcn_cvt_pkrtz(c, d);
    return r.u;
}

// ---------------------------------------------------------------------------
// K1 (grid 64): build D (blk0 -> d_out), ssq partials -> ws[16+b], beta table
// (blk0 lane0 -> ws[80..179]), pack f16 hi/lo MFMA A-operand images for D
// (GEMM1 16x16x32) and D^T (GEMM2 32x32x16).
__global__ __launch_bounds__(256) void k_build(const float* __restrict__ rr,
                                               const float* __restrict__ th,
                                               float* __restrict__ out,
                                               float* __restrict__ ws) {
    __shared__ float Dl[TT*KK];
    __shared__ float red[256];
    int tid = threadIdx.x, b = blockIdx.x;
    for (int e = tid; e < TT*KK; e += 256) {
        int t = e / KK, k = e % KK;
        float v;
        if (k == 0) v = 1.f;
        else if (k <= PP) { int p = k - 1;     v = powf(rr[p], (float)t) * cosf((float)t * th[p]); }
        else              { int p = k - 1 - PP; v = powf(rr[p], (float)t) * sinf((float)t * th[p]); }
        Dl[e] = v;
        if (b == 0) out[D_OFF + e] = v;
    }
    // beta momentum table: identical float ops to the original in-loop chain
    if (b == 0 && tid == 0) {
        float t = 0.5f * (1.f + sqrtf(5.f));   // t_1 (after peeled iter 0)
        ws[80] = 0.f;
        for (int it = 1; it < NITER; ++it) {
            float tn = 0.5f * (1.f + sqrtf(1.f + 4.f*t*t));
            ws[80 + it] = (t - 1.f) / tn;
            t = tn;
        }
    }
    __syncthreads();
    float ssq = 0.f;
    for (int p = b*256 + tid; p < KK*KK; p += 64*256) {
        int k1 = p / KK, k2 = p % KK;
        float s = 0.f;
        for (int t = 0; t < TT; ++t) s += Dl[t*KK + k1] * Dl[t*KK + k2];
        ssq += s * s;
    }
    red[tid] = ssq;
    __syncthreads();
    for (int off = 128; off > 0; off >>= 1) {
        if (tid < off) red[tid] += red[tid + off];
        __syncthreads();
    }
    if (tid == 0) { ws[16 + b] = red[0]; if (b == 0) ws[1] = 0.f; }

    // A1: lane l holds A[m=l&15][k=8*(l>>4)+i] per 16x16x32 tile
    _Float16* a1 = (_Float16*)(ws + WSA1);
    for (int e = b*256 + tid; e < 3*6*2*512; e += 64*256) {
        int fp = e & 511, r = e >> 9;       // r = (Mt1*6+kt)*2 + h
        int h = r & 1, mk = r >> 1;
        int l = fp >> 3, i = fp & 7;
        int t = (mk / 6) * 16 + (l & 15);
        int j = (mk % 6) * 32 + ((l >> 4) << 3) + i;
        float v = (t < TT && j < KK) ? Dl[t*KK + j] : 0.f;
        _Float16 hi = (_Float16)v;
        a1[e] = h ? (_Float16)(v - (float)hi) : hi;
    }
    // A2 (D^T): lane l holds A[m=l&31][k=8*(l>>5)+i] per 32x32x16 tile
    _Float16* a2 = (_Float16*)(ws + WSA2);
    for (int e = b*256 + tid; e < 6*3*2*512; e += 64*256) {
        int fp = e & 511, r = e >> 9;       // r = (Mt2*3+kt)*2 + h
        int h = r & 1, mk = r >> 1;
        int l = fp >> 3, i = fp & 7;
        int m = (mk / 3) * 32 + (l & 31);
        int t = (mk % 3) * 16 + ((l >> 5) << 3) + i;
        float v = (m < KK && t < TT) ? Dl[t*KK + m] : 0.f;
        _Float16 hi = (_Float16)v;
        a2[e] = h ? (_Float16)(v - (float)hi) : hi;
    }
}

// ---------------------------------------------------------------------------
// K2: fused FISTA, grid 256 (one n per block), 768 threads = 12 waves.
// Verified best (R9, 280.3us total): issue-sum budget 717 cyc/iter =
// VALU 407 + MFMA 162 + other 148 at power-limited ~633 MHz. Structural
// attacks all tested: Gram 1-barrier (R8: cycle-neutral, clock -16%),
// f16 state (R10: absmax 0.60 fail), coop fusion (R11: +27us launch cost),
// 384-thr split (R3: no co-residency). This is the floor configuration.
// GEMM1 (z = D y): 16x16x32, wave = (Mt1 = w>>2, nt1 = w&3).
// GEMM2 (w = D^T z): 32x32x16, wave = (Mt2 = w>>1, nh = w&1).
template<int PHASE>
__global__ __launch_bounds__(768, 3) void k_fista(float* __restrict__ ws,
                                                  const float* __restrict__ x,
                                                  float* __restrict__ out) {
    __shared__ _Float16 Ys[4*6*512];   // 24,576 B: [nt16:4][kt32:6][512]
    __shared__ _Float16 Zs[2*3*512];   //  6,144 B: [nh:2][kt16:3][512]
    __shared__ float bts[NITER];       //    400 B: beta momentum table
    int tid = threadIdx.x;
    int w = tid >> 6, l = tid & 63;
    int n = blockIdx.x;

    // ---- stage x -> Zs (f16 hi, GEMM2 B-frag image, k-dim = t)
    const float* xb = x + n*TT*FF;
    for (int e = tid; e < 3072; e += 768) {
        int t = e >> 6, c64 = e & 63;
        float v = (t < TT && c64 < FF) ? xb[t*FF + c64] : 0.f;
        int nh = c64 >> 5, c = c64 & 31;
        int kt = t >> 4, kk = t & 15;
        int ofs = ((((kk >> 3) << 5) + c) << 3) + (kk & 7);
        Zs[((nh*3 + kt) << 9) + ofs] = (_Float16)v;
    }
    if (tid < NITER) bts[tid] = ws[80 + tid];

    // ---- L-norm: wave butterfly over the 64 k_build partials
    float pv = ws[16 + l];
    #pragma unroll
    for (int off = 32; off > 0; off >>= 1) pv += __shfl_xor(pv, off);
    float linv = rsqrtf(pv);

    int Mt1 = w >> 2, nt1 = w & 3;     // GEMM1 role
    int Mt2 = w >> 1, nh  = w & 1;     // GEMM2 role
    const _Float16* a1g = (const _Float16*)(ws + WSA1);
    const _Float16* a2g = (const _Float16*)(ws + WSA2);
    half8 a1[6][2], a2[3][2];
    #pragma unroll
    for (int kt = 0; kt < 6; ++kt)
        #pragma unroll
        for (int h = 0; h < 2; ++h)
            a1[kt][h] = *(const half8*)(a1g + ((((Mt1*6 + kt)*2 + h) << 9) + (l << 3)));
    #pragma unroll
    for (int kt = 0; kt < 3; ++kt)
        #pragma unroll
        for (int h = 0; h < 2; ++h)
            a2[kt][h] = *(const half8*)(a2g + ((((Mt2*3 + kt)*2 + h) << 9) + (l << 3)));

    // held zero accumulators (loop-invariant C operands for first MFMA)
    f32x16 z16;
    #pragma unroll
    for (int r = 0; r < 16; ++r) z16[r] = 0.f;
    f32x4 z4 = {0.f, 0.f, 0.f, 0.f};
    __syncthreads();

    // ---- head GEMM2: acc = D^T @ f16(x)  (hi+lo, full precision for c)
    f32x16 acc;
    {
        half8 bh = *(const half8*)&Zs[((nh*3 + 0) << 9) + (l << 3)];
        acc = MFMA_32(a2[0][0], bh, z16);
        acc = MFMA_32(a2[0][1], bh, acc);
    }
    #pragma unroll
    for (int kt = 1; kt < 3; ++kt) {
        half8 bh = *(const half8*)&Zs[((nh*3 + kt) << 9) + (l << 3)];
        acc = MFMA_32(a2[kt][0], bh, acc);
        acc = MFMA_32(a2[kt][1], bh, acc);
    }

    int cl = l & 15, q = l >> 4;       // GEMM1 C addressing
    int nloc = l & 31, s5 = l >> 5;    // GEMM2 C addressing
    int nt16 = nh*2 + (nloc >> 4);
    int fcol = nh*32 + nloc;           // global f of owned columns
    int zofs = ((((q >> 1) << 5) + (nt1 & 1)*16 + cl) << 3) + ((q & 1) << 2);
    int znh = nt1 >> 1;
    // blo/bhi: folded shrink bounds (xn = ay - med3(ay, blo, bhi))
    float blo[4][4], bhi[4][4], xo[4][4], yo[4][4];
    float wlv = LAMB * linv;           // uniform shrink width (phase 0)

    // ---- peeled iteration 0: x1 = shrink(c), y1 = x1
    {
        float fac = 0.f;
        if (PHASE) fac = (float)KK * LAMB * linv * rsqrtf(ws[1]);
        #pragma unroll
        for (int gq = 0; gq < 4; ++gq) {
            int k0 = Mt2*32 + 8*gq + 4*s5;
            float yn4[4];
            #pragma unroll
            for (int j = 0; j < 4; ++j) {
                int k = k0 + j;
                float cvv = 0.f, wle;
                if (PHASE) {
                    wle = 0.f;
                    if (k < KK && fcol < FF) {
                        cvv = linv * acc[gq*4 + j];
                        float prev = out[(size_t)n*KK*FF + k*FF + fcol];
                        wle = fac / (fabsf(prev) + 0.01f);
                    }
                } else {
                    wle = wlv;
                    if (k < KK && fcol < FF) cvv = linv * acc[gq*4 + j];
                }
                blo[gq][j] = -cvv - wle;   // lower clamp bound (on ay)
                bhi[gq][j] = wle - cvv;    // upper clamp bound (on ay)
                float xn = cvv - __builtin_amdgcn_fmed3f(cvv, -wle, wle);
                xo[gq][j] = xn; yo[gq][j] = xn;
                yn4[j] = xn;
            }
            int yofs = ((gq*16 + cl) << 3) + (s5 << 2);
            *(unsigned long long*)&Ys[((nt16*6 + Mt2) << 9) + yofs] =
                pack4(yn4[0], yn4[1], yn4[2], yn4[3]);
        }
    }
    __syncthreads();

    for (int it = 1; it < NITER; ++it) {
        float beta = bts[it];
        // ---- GEMM1: z(Mt1, nt1) = D_hi @ f16(y)  (hi-only in-loop)
        f32x4 zz;
        {
            half8 bh = *(const half8*)&Ys[((nt1*6 + 0) << 9) + (l << 3)];
            zz = MFMA_16(a1[0][0], bh, z4);
        }
        #pragma unroll
        for (int kt = 1; kt < 6; ++kt) {
            half8 bh = *(const half8*)&Ys[((nt1*6 + kt) << 9) + (l << 3)];
            zz = MFMA_16(a1[kt][0], bh, zz);
        }
        *(unsigned long long*)&Zs[((znh*3 + Mt1) << 9) + zofs] =
            pack4(zz[0], zz[1], zz[2], zz[3]);
        __syncthreads();

        // ---- GEMM2: acc(Mt2, nh) = D_hi^T @ f16(z)  (hi-only in-loop)
        {
            half8 bh = *(const half8*)&Zs[((nh*3 + 0) << 9) + (l << 3)];
            acc = MFMA_32(a2[0][0], bh, z16);
        }
        #pragma unroll
        for (int kt = 1; kt < 3; ++kt) {
            half8 bh = *(const half8*)&Zs[((nh*3 + kt) << 9) + (l << 3)];
            acc = MFMA_32(a2[kt][0], bh, acc);
        }
        // ---- epilogue: folded-bound shrink + momentum, rebuild y image
        #pragma unroll
        for (int gq = 0; gq < 4; ++gq) {
            float yn4[4];
            #pragma unroll
            for (int j = 0; j < 4; ++j) {
                float ay = fmaf(-linv, acc[gq*4 + j], yo[gq][j]);
                float xn = ay - __builtin_amdgcn_fmed3f(ay, blo[gq][j], bhi[gq][j]);
                float yn = fmaf(beta, xn - xo[gq][j], xn);
                xo[gq][j] = xn; yo[gq][j] = yn;
                yn4[j] = yn;
            }
            int yofs = ((gq*16 + cl) << 3) + (s5 << 2);
            *(unsigned long long*)&Ys[((nt16*6 + Mt2) << 9) + yofs] =
                pack4(yn4[0], yn4[1], yn4[2], yn4[3]);
        }
        __syncthreads();
    }

    // ---- store final code
    #pragma unroll
    for (int gq = 0; gq < 4; ++gq) {
        int k0 = Mt2*32 + 8*gq + 4*s5;
        #pragma unroll
        for (int j = 0; j < 4; ++j) {
            int k = k0 + j;
            if (k < KK && fcol < FF)
                out[(size_t)n*KK*FF + k*FF + fcol] = xo[gq][j];
        }
    }

    if (!PHASE) {
        // ---- fused wnorm
        float s = 0.f;
        #pragma unroll
        for (int gq = 0; gq < 4; ++gq) {
            int k0 = Mt2*32 + 8*gq + 4*s5;
            #pragma unroll
            for (int j = 0; j < 4; ++j) {
                if (k0 + j < KK && fcol < FF) {
                    float wn = 1.f / (fabsf(xo[gq][j]) + 0.01f);
                    s += wn * wn;
                }
            }
        }
        #pragma unroll
        for (int off = 32; off > 0; off >>= 1) s += __shfl_down(s, off);
        float* red = (float*)Zs;
        if (l == 0) red[w] = s;
        __syncthreads();
        if (tid == 0) {
            float t = 0.f;
            #pragma unroll
            for (int i = 0; i < 12; ++i) t += red[i];
            atomicAdd(&ws[1], t);
        }
    } else {
        // ---- fused reconst: f16(code) into Ys, GEMM1 pass (hi+lo), store
        #pragma unroll
        for (int gq = 0; gq < 4; ++gq) {
            int yofs = ((gq*16 + cl) << 3) + (s5 << 2);
            *(unsigned long long*)&Ys[((nt16*6 + Mt2) << 9) + yofs] =
                pack4(xo[gq][0], xo[gq][1], xo[gq][2], xo[gq][3]);
        }
        __syncthreads();
        f32x4 za, zb;
        {
            half8 bh = *(const half8*)&Ys[((nt1*6 + 0) << 9) + (l << 3)];
            za = MFMA_16(a1[0][0], bh, z4);
            zb = MFMA_16(a1[0][1], bh, z4);
        }
        #pragma unroll
        for (int kt = 1; kt < 6; ++kt) {
            half8 bh = *(const half8*)&Ys[((nt1*6 + kt) << 9) + (l << 3)];
            za = MFMA_16(a1[kt][0], bh, za);
            zb = MFMA_16(a1[kt][1], bh, zb);
        }
        f32x4 zz = za + zb;
        int fcol2 = nt1*16 + cl;
        #pragma unroll
        for (int r = 0; r < 4; ++r) {
            int t = Mt1*16 + q*4 + r;
            if (t < TT && fcol2 < FF)
                out[R_OFF + (size_t)n*TT*FF + t*FF + fcol2] = zz[r];
        }
    }
}

// ---------------------------------------------------------------------------
extern "C" void kernel_launch(void* const* d_in, const int* in_sizes, int n_in,
                              void* d_out, int out_size, void* d_ws, size_t ws_size,
                              hipStream_t stream) {
    const float* x  = (const float*)d_in[0];
    const float* rr = (const float*)d_in[1];
    const float* th = (const float*)d_in[2];
    float* out = (float*)d_out;
    float* ws  = (float*)d_ws;

    hipLaunchKernelGGL(k_build, dim3(64), dim3(256), 0, stream, rr, th, out, ws);
    hipLaunchKernelGGL(HIP_KERNEL_NAME(k_fista<0>), dim3(NB), dim3(768), 0, stream, ws, x, out);
    hipLaunchKernelGGL(HIP_KERNEL_NAME(k_fista<1>), dim3(NB), dim3(768), 0, stream, ws, x, out);
}